// Round 3
// baseline (1449.959 us; speedup 1.0000x reference)
//
#include <hip/hip_runtime.h>

// CAGenerator: 64-step neural CA — TWO dispatches/step, weight-reuse split.
// R18: per-CU weight stream cut 2.45x (R17 A/B showed per-CU-byte-bound).
//  kBH: 256 blocks = 8 H-slabs x 32 row-groups (slab = blk&7 -> XCD-local L2).
//       Block computes 64 H-ch x 8 rows. Slab weights (96 KB) staged ONCE to
//       LDS via global_load_lds (8KB chunks, ring-3, counted vmcnt, raw
//       s_barrier) and shared by all 8 waves (1 row/wave). Masked state msT
//       rebuilt from Um (f16 px-major) + live mask. H -> global (octets).
//  kU:  256 blocks x 256 thr (1 row): rebuilds fp32 S row (same live math,
//       bitwise-identical mask), upd = W3*H full-K from global rings,
//       writes U (fp32 ch-major), Um (f16 px-major), A (alpha plane).
// kF: dout = U63 ch0 * live63.
// Folded: Wc = W2@W1 (512x720), bc = W2@b1+b2. mask=uniform()<1.0 -> no RNG.

#define NPIX 8192
#define T_ALIVE 0.01f

typedef _Float16 f16;
typedef __attribute__((ext_vector_type(8)))  _Float16 h8_t;
typedef __attribute__((ext_vector_type(4)))  _Float16 h4_t;
typedef __attribute__((ext_vector_type(16))) float    fx16;

__device__ __forceinline__ void gld16(const f16* g, f16* l)
{
    __builtin_amdgcn_global_load_lds(
        (const __attribute__((address_space(1))) unsigned int*)(const void*)g,
        (__attribute__((address_space(3))) unsigned int*)(void*)l, 16, 0, 0);
}

// ---------------------------------------------------------------------------
// Prep
// ---------------------------------------------------------------------------
__global__ __launch_bounds__(256) void tr512(
    const float* __restrict__ W2, float* __restrict__ W2T)
{
    __shared__ float t[32][33];
    const int bx = blockIdx.x & 15, by = blockIdx.x >> 4;
    const int x = threadIdx.x & 31, y8 = threadIdx.x >> 5;
#pragma unroll
    for (int r = 0; r < 32; r += 8)
        t[r + y8][x] = W2[(size_t)(by * 32 + r + y8) * 512 + bx * 32 + x];
    __syncthreads();
#pragma unroll
    for (int r = 0; r < 32; r += 8)
        W2T[(size_t)(bx * 32 + r + y8) * 512 + by * 32 + x] = t[x][r + y8];
}

__global__ __launch_bounds__(256) void wc32(
    const float* __restrict__ W2T, const float* __restrict__ W1,
    float* __restrict__ Wc)
{
    __shared__ float As[16][32];
    __shared__ float Bs[16][32];
    const int tid = threadIdx.x;
    const int ty = tid >> 3, tx = tid & 7;
    const int m0 = blockIdx.y * 32, n0 = blockIdx.x * 32;
    float acc[4] = {0.f, 0.f, 0.f, 0.f};

    for (int k0 = 0; k0 < 512; k0 += 16) {
#pragma unroll
        for (int t = 0; t < 2; ++t) {
            const int idx = tid + t * 256;
            const int r = idx >> 5, c = idx & 31;
            As[r][c] = W2T[(size_t)(k0 + r) * 512 + m0 + c];
            const int n = n0 + c;
            Bs[r][c] = (n < 720) ? W1[(size_t)(k0 + r) * 720 + n] : 0.f;
        }
        __syncthreads();
#pragma unroll
        for (int kk = 0; kk < 16; ++kk) {
            const float a = As[kk][ty];
#pragma unroll
            for (int j = 0; j < 4; ++j)
                acc[j] = fmaf(a, Bs[kk][tx * 4 + j], acc[j]);
        }
        __syncthreads();
    }
    const int m = m0 + ty;
#pragma unroll
    for (int j = 0; j < 4; ++j) {
        const int n = n0 + tx * 4 + j;
        if (n < 720) Wc[(size_t)m * 720 + n] = acc[j];
    }
}

__global__ __launch_bounds__(256) void bc_k(
    const float* __restrict__ W2, const float* __restrict__ b1,
    const float* __restrict__ b2, float* __restrict__ bc)
{
    const int m = blockIdx.x * 256 + threadIdx.x;
    if (m >= 512) return;
    float a = b2[m];
    for (int h = 0; h < 512; ++h) a += W2[m * 512 + h] * b1[h];
    bc[m] = a;
}

// Slab-major weight frags: Wh[(((h*48+ck)*2+i)*64+lane)*8+e], K permuted
// (kp = tap*80+ci), ck 45..47 zero-padded. Slab h holds m-tiles 2h, 2h+1.
__global__ __launch_bounds__(256) void swz_wh(
    const float* __restrict__ Wc, f16* __restrict__ Wh)
{
    const int idx = blockIdx.x * 256 + threadIdx.x;
    if (idx >= 49152) return;
    const int lane = idx & 63;
    int t = idx >> 6;
    const int i = t & 1; t >>= 1;
    const int ck = t % 48, h = t / 48;
    const int mtg = h * 2 + i;
    const int m = mtg * 32 + (lane & 31);
    const int k0 = ck * 16 + (lane >> 5) * 8;
    h8_t v;
#pragma unroll
    for (int j = 0; j < 8; ++j) {
        const int kp = k0 + j;
        if (kp < 720) {
            const int tap = kp / 80, ci = kp - tap * 80;
            v[j] = (f16)Wc[(size_t)m * 720 + ci * 9 + tap];
        } else {
            v[j] = (f16)0.f;
        }
    }
    *(h8_t*)(Wh + (size_t)idx * 8) = v;
}

// 32x32x16 A-frags for W3 (80x512 padded to 96 rows).
__global__ __launch_bounds__(256) void swz_w32(
    const float* __restrict__ W3, f16* __restrict__ W3sw2)
{
    const int idx = blockIdx.x * 256 + threadIdx.x;
    if (idx >= 32 * 3 * 64) return;
    const int lane = idx & 63;
    const int t = idx >> 6;
    const int mt = t % 3, ks2 = t / 3;
    const int m = mt * 32 + (lane & 31);
    const int k0 = ks2 * 16 + (lane >> 5) * 8;
    h8_t v;
#pragma unroll
    for (int j = 0; j < 8; ++j)
        v[j] = (f16)((m < 80) ? W3[(size_t)m * 512 + k0 + j] : 0.f);
    *(h8_t*)(W3sw2 + (size_t)idx * 8) = v;
}

// Seed: U_{-1} := S_0 (fp32 ch-major), Um_{-1} := f16 px-major, A_{-1} := ch0.
__global__ __launch_bounds__(256) void seed3(
    const float* __restrict__ z, float* __restrict__ U0,
    f16* __restrict__ Um0, float* __restrict__ A0)
{
    const int idx = blockIdx.x * 256 + threadIdx.x;
    if (idx >= 640) return;
    const int b = idx / 80, c = idx - b * 80;
    const int n = b * 1024 + 16 * 32 + 16;
    const float v = (c == 0) ? 1.f : z[b * 100 + (c - 1)];
    U0[(size_t)c * NPIX + n] = v;
    Um0[(size_t)n * 80 + c] = (f16)v;
    if (c == 0) A0[n] = 1.f;
}

// ---------------------------------------------------------------------------
// kBH: H-slab x row-group. grid 256 x 512 thr. blk: h = blk&7 (slab/XCD),
//   g = blk>>3; b = g>>2, y0 = (g&3)*8; rows y0..y0+7, wave w = row y0+w.
//   Computes H channels [h*64, h*64+64) for 8 rows; weights LDS-shared.
// ---------------------------------------------------------------------------
__global__ __launch_bounds__(512) void kBH(
    const f16* __restrict__ Wh, const float* __restrict__ bc,
    const f16* __restrict__ Um, const float* __restrict__ Nw,  // U_prev (plane0)
    const float* __restrict__ Ap, f16* __restrict__ Hout)
{
    __shared__ f16   msT[27200];     // ((cc*10 + r)*34 + xi) octets x 8 halfs
    __shared__ f16   Aring[12288];   // 3 slots x 4096 halfs (8 KB each)
    __shared__ float bcL[64];
    __shared__ float N12[384];
    __shared__ float A12[384];
    __shared__ float live10[320];

    const int tid = threadIdx.x;
    const int lane = tid & 63, w = tid >> 6;
    const int li = lane & 31, q2 = lane >> 5;
    const int blk = blockIdx.x;
    const int h = blk & 7, g = blk >> 3;
    const int b = g >> 2, y0 = (g & 3) * 8;
    const int gb = b * 1024;
    const f16* Whb = Wh + (size_t)h * 49152;

    // prologue: issue weight chunks 0..2 (async, overlap the build)
#pragma unroll
    for (int c = 0; c < 3; ++c)
        gld16(Whb + (size_t)c * 4096 + w * 512 + lane * 8,
              Aring + (size_t)c * 4096 + w * 512);

    if (tid < 64) bcL[tid] = bc[h * 64 + tid];

    // ---------------- build: live mask + masked f16 state -----------------
    if (tid < 384) {
        const int r = tid >> 5, x = tid & 31, yy = y0 - 2 + r;
        const bool ok = ((unsigned)yy < 32u);
        N12[tid] = ok ? Nw[gb + yy * 32 + x] : -1e30f;
        A12[tid] = ok ? Ap[gb + yy * 32 + x] : -1e30f;
    }
    __syncthreads();

    if (tid < 320) {   // live rows y0-1..y0+8
        const int r = tid >> 5, x = tid & 31;
        float mN = -1e30f, mA = -1e30f;
#pragma unroll
        for (int rr = 0; rr < 3; ++rr)
#pragma unroll
            for (int dx = -1; dx <= 1; ++dx) {
                const int xx = x + dx;
                if ((unsigned)xx < 32u) {
                    mN = fmaxf(mN, N12[(r + rr) * 32 + xx]);
                    mA = fmaxf(mA, A12[(r + rr) * 32 + xx]);
                }
            }
        live10[tid] = (mN > T_ALIVE && mA > T_ALIVE) ? 1.f : 0.f;
    }
    __syncthreads();

    {   // msT = Um * live, 10 rows x 10 cc x 32 px; plus halo cols
        h8_t zz;
#pragma unroll
        for (int j = 0; j < 8; ++j) zz[j] = (f16)0.f;
        for (int q = tid; q < 3200; q += 512) {
            const int r = q / 320, rem = q - r * 320;
            const int cc = rem >> 5, x = rem & 31;
            const int yy = y0 - 1 + r;
            h8_t v = zz;
            if (((unsigned)yy < 32u) && live10[r * 32 + x] != 0.f)
                v = *(const h8_t*)(Um + (size_t)(gb + yy * 32 + x) * 80 + cc * 8);
            *(h8_t*)(msT + (size_t)((cc * 10 + r) * 34 + x + 1) * 8) = v;
        }
        if (tid < 200) {   // halo columns xi = 0, 33
            const int cc = tid / 20, rem = tid % 20;
            const int r = rem >> 1, xi = (rem & 1) * 33;
            *(h8_t*)(msT + (size_t)((cc * 10 + r) * 34 + xi) * 8) = zz;
        }
    }
    __syncthreads();

    // ---------------- main loop: 12 chunks x 4 ks, LDS-shared weights -----
    int pxh[9];
#pragma unroll
    for (int t = 0; t < 9; ++t)
        pxh[t] = ((t / 3) * 34 + li + (t % 3)) * 8;

    fx16 acc0, acc1;
#pragma unroll
    for (int r = 0; r < 16; ++r) { acc0[r] = 0.f; acc1[r] = 0.f; }

    const int wbase = w * 272;   // w*34*8 halfs

    for (int c = 0; c < 12; ++c) {
        asm volatile("s_waitcnt vmcnt(2)" ::: "memory");
        __builtin_amdgcn_s_barrier();
        __builtin_amdgcn_sched_barrier(0);
        const f16* slot = Aring + (c % 3) * 4096;
#pragma unroll
        for (int kk = 0; kk < 4; ++kk) {
            const int ks = c * 4 + kk;
            if (ks < 45) {
                const int o = 2 * ks + q2;
                const int cc = o % 10, t = o / 10;
                const h8_t bf = *(const h8_t*)(msT + cc * 2720 + wbase + pxh[t]);
                const h8_t a0 = *(const h8_t*)(slot + (kk * 2 + 0) * 512 + lane * 8);
                const h8_t a1 = *(const h8_t*)(slot + (kk * 2 + 1) * 512 + lane * 8);
                acc0 = __builtin_amdgcn_mfma_f32_32x32x16_f16(a0, bf, acc0, 0, 0, 0);
                acc1 = __builtin_amdgcn_mfma_f32_32x32x16_f16(a1, bf, acc1, 0, 0, 0);
            }
        }
        __builtin_amdgcn_sched_barrier(0);
        __builtin_amdgcn_s_barrier();
        if (c + 3 < 12)
            gld16(Whb + (size_t)(c + 3) * 4096 + w * 512 + lane * 8,
                  Aring + (size_t)(c % 3) * 4096 + w * 512);
    }

    // ---------------- epilogue: relu(acc + bc) -> H global ----------------
    const int R = b * 32 + y0 + w;
#pragma unroll
    for (int i = 0; i < 2; ++i) {
#pragma unroll
        for (int aa = 0; aa < 4; ++aa) {
            const int chl = i * 32 + 8 * aa + 4 * q2;
            const int co = h * 8 + i * 4 + aa;
            h4_t v4;
            const fx16& ac = i ? acc1 : acc0;
#pragma unroll
            for (int rb = 0; rb < 4; ++rb)
                v4[rb] = (f16)fmaxf(ac[aa * 4 + rb] + bcL[chl + rb], 0.f);
            *(h4_t*)(Hout + ((size_t)(R * 64 + co) * 32 + li) * 8 + 4 * q2) = v4;
        }
    }
}

// ---------------------------------------------------------------------------
// kU: one row per block. grid 256 x 256 thr. blk = R = b*32+y.
//   Rebuild fp32 S row (same live math as kBH), upd = W3*H (global rings),
//   write U fp32 + Um f16 px-major + A plane.
// ---------------------------------------------------------------------------
__global__ __launch_bounds__(256) void kU(
    const f16* __restrict__ W3sw2, const float* __restrict__ b3,
    const f16* __restrict__ Hin, const float* __restrict__ Uin,
    const float* __restrict__ Ain,
    float* __restrict__ Uout, f16* __restrict__ Umout,
    float* __restrict__ Aout)
{
    __shared__ float SrowL[2560];
    __shared__ float UrowL[2560];
    __shared__ float N3[96];
    __shared__ float A3[96];
    __shared__ float liveR[32];
    __shared__ float b3L[80];

    const int tid = threadIdx.x;
    const int lane = tid & 63, w = tid >> 6;
    const int li = lane & 31, q2 = lane >> 5;
    const int blk = blockIdx.x;
    const int b = blk >> 5, y = blk & 31;
    const int gb = b * 1024;
    const int base = gb + y * 32;
    const f16* Hrow = Hin + (size_t)blk * 16384;

    // prologue: W3 + H rings (waves 0..2)
    h8_t ar[8], hr[8];
    if (w < 3) {
#pragma unroll
        for (int pk = 0; pk < 8; ++pk) {
            ar[pk] = *(const h8_t*)(W3sw2 + (((size_t)pk * 3 + w) * 64 + lane) * 8);
            hr[pk] = *(const h8_t*)(Hrow + ((size_t)(pk * 2 + q2) * 32 + li) * 8);
        }
    }
    if (tid < 80) b3L[tid] = b3[tid];
    if (tid < 96) {
        const int r = tid >> 5, x = tid & 31, yy = y - 1 + r;
        const bool ok = ((unsigned)yy < 32u);
        N3[tid] = ok ? Uin[gb + yy * 32 + x] : -1e30f;
        A3[tid] = ok ? Ain[gb + yy * 32 + x] : -1e30f;
    }
    __syncthreads();

    if (tid < 32) {
        float mN = -1e30f, mA = -1e30f;
#pragma unroll
        for (int rr = 0; rr < 3; ++rr)
#pragma unroll
            for (int dx = -1; dx <= 1; ++dx) {
                const int xx = tid + dx;
                if ((unsigned)xx < 32u) {
                    mN = fmaxf(mN, N3[rr * 32 + xx]);
                    mA = fmaxf(mA, A3[rr * 32 + xx]);
                }
            }
        liveR[tid] = (mN > T_ALIVE && mA > T_ALIVE) ? 1.f : 0.f;
    }
    __syncthreads();

    // S row (fp32) + A_out
#pragma unroll
    for (int it = 0; it < 10; ++it) {
        const int q = tid + it * 256;
        const int ch = q >> 5, x = q & 31;
        const float v = Uin[(size_t)ch * NPIX + base + x] * liveR[x];
        SrowL[q] = v;
        if (ch == 0) Aout[base + x] = v;
    }
    __syncthreads();

    // phase 2: upd = W3*H full-K (waves 0..2); U = S + upd + b3
    if (w < 3) {
        fx16 acc3;
#pragma unroll
        for (int r = 0; r < 16; ++r) acc3[r] = 0.f;
#pragma unroll
        for (int ks2 = 0; ks2 < 32; ++ks2) {
            const h8_t a = ar[ks2 & 7];
            const h8_t bf = hr[ks2 & 7];
            if (ks2 + 8 < 32) {
                ar[ks2 & 7] = *(const h8_t*)(W3sw2 +
                    (((size_t)(ks2 + 8) * 3 + w) * 64 + lane) * 8);
                hr[ks2 & 7] = *(const h8_t*)(Hrow +
                    ((size_t)((ks2 + 8) * 2 + q2) * 32 + li) * 8);
            }
            acc3 = __builtin_amdgcn_mfma_f32_32x32x16_f16(a, bf, acc3, 0, 0, 0);
        }
#pragma unroll
        for (int aa = 0; aa < 4; ++aa)
#pragma unroll
            for (int rb = 0; rb < 4; ++rb) {
                const int ch = w * 32 + rb + 8 * aa + 4 * q2;
                if (ch < 80) {
                    const float uv = SrowL[ch * 32 + li] + acc3[aa * 4 + rb] + b3L[ch];
                    Uout[(size_t)ch * NPIX + base + li] = uv;
                    UrowL[ch * 32 + li] = uv;
                }
            }
    }
    __syncthreads();

    // Um (f16 px-major) from UrowL
    for (int q = tid; q < 640; q += 256) {
        const int cq = q >> 5, x = q & 31;
        h4_t v4;
#pragma unroll
        for (int rb = 0; rb < 4; ++rb)
            v4[rb] = (f16)UrowL[(cq * 4 + rb) * 32 + x];
        *(h4_t*)(Umout + (size_t)(base + x) * 80 + cq * 4) = v4;
    }
}

// ---------------------------------------------------------------------------
// kF: dout = U63 ch0 * live63. grid 256 x 128 thr.
// ---------------------------------------------------------------------------
__global__ __launch_bounds__(128) void kF(
    const float* __restrict__ Uf, const float* __restrict__ Af,
    float* __restrict__ dout)
{
    __shared__ float N3[96];
    __shared__ float A3[96];
    const int tid = threadIdx.x;
    const int blk = blockIdx.x;
    const int b = blk >> 5, y = blk & 31;
    const int gb = b * 1024;

    if (tid < 96) {
        const int r = tid >> 5, x = tid & 31, yy = y - 1 + r;
        const bool ok = ((unsigned)yy < 32u);
        N3[tid] = ok ? Uf[gb + yy * 32 + x] : -1e30f;
        A3[tid] = ok ? Af[gb + yy * 32 + x] : -1e30f;
    }
    __syncthreads();

    if (tid < 32) {
        float mN = -1e30f, mA = -1e30f;
#pragma unroll
        for (int rr = 0; rr < 3; ++rr)
#pragma unroll
            for (int dx = -1; dx <= 1; ++dx) {
                const int xx = tid + dx;
                if ((unsigned)xx < 32u) {
                    mN = fmaxf(mN, N3[rr * 32 + xx]);
                    mA = fmaxf(mA, A3[rr * 32 + xx]);
                }
            }
        const float lv = (mN > T_ALIVE && mA > T_ALIVE) ? 1.f : 0.f;
        dout[gb + y * 32 + tid] = Uf[gb + y * 32 + tid] * lv;
    }
}

// ---------------------------------------------------------------------------
extern "C" void kernel_launch(void* const* d_in, const int* in_sizes, int n_in,
                              void* d_out, int out_size, void* d_ws, size_t ws_size,
                              hipStream_t stream)
{
    const float* z  = (const float*)d_in[0];
    const float* W1 = (const float*)d_in[1];   // 512 x 720
    const float* b1 = (const float*)d_in[2];
    const float* W2 = (const float*)d_in[3];   // 512 x 512
    const float* b2 = (const float*)d_in[4];
    const float* W3 = (const float*)d_in[5];   // 80 x 512
    const float* b3 = (const float*)d_in[6];

    char* ws = (char*)d_ws;
    float* U0    = (float*)ws;  ws += (size_t)80 * NPIX * 4;
    float* U1    = (float*)ws;  ws += (size_t)80 * NPIX * 4;
    f16*   Um0   = (f16*)ws;   ws += (size_t)NPIX * 80 * 2;
    f16*   Um1   = (f16*)ws;   ws += (size_t)NPIX * 80 * 2;
    float* A0    = (float*)ws;  ws += (size_t)NPIX * 4;
    float* A1    = (float*)ws;  ws += (size_t)NPIX * 4;
    f16*   Hbuf  = (f16*)ws;   ws += (size_t)256 * 64 * 32 * 8 * 2;
    float* bc    = (float*)ws;  ws += 512 * 4;
    float* Wc    = (float*)ws;  ws += (size_t)512 * 720 * 4;
    float* W2T   = (float*)ws;  ws += (size_t)512 * 512 * 4;
    f16*   Wh    = (f16*)ws;   ws += (size_t)49152 * 8 * 2;
    f16*   W3sw2 = (f16*)ws;   ws += (size_t)32 * 3 * 64 * 8 * 2;

    hipMemsetAsync(U0, 0, (size_t)80 * NPIX * 4, stream);
    hipMemsetAsync(Um0, 0, (size_t)NPIX * 80 * 2, stream);
    hipMemsetAsync(A0, 0, (size_t)NPIX * 4, stream);
    seed3<<<3, 256, 0, stream>>>(z, U0, Um0, A0);
    tr512<<<256, 256, 0, stream>>>(W2, W2T);
    wc32<<<dim3(23, 16), 256, 0, stream>>>(W2T, W1, Wc);
    bc_k<<<2, 256, 0, stream>>>(W2, b1, b2, bc);
    swz_wh<<<192, 256, 0, stream>>>(Wc, Wh);
    swz_w32<<<24, 256, 0, stream>>>(W3, W3sw2);

    float* Uc = U0;  float* Un = U1;
    f16*   Mc = Um0; f16*   Mn = Um1;
    float* Ac = A0;  float* An = A1;
    for (int s = 0; s < 64; ++s) {
        kBH<<<256, 512, 0, stream>>>(Wh, bc, Mc, Uc, Ac, Hbuf);
        kU<<<256, 256, 0, stream>>>(W3sw2, b3, Hbuf, Uc, Ac, Un, Mn, An);
        float* t = Uc; Uc = Un; Un = t;
        f16*   m = Mc; Mc = Mn; Mn = m;
        float* a = Ac; Ac = An; An = a;
    }
    kF<<<256, 128, 0, stream>>>(Uc, Ac, (float*)d_out);
}

// Round 5
// 1155.920 us; speedup vs baseline: 1.2544x; 1.2544x over previous
//
#include <hip/hip_runtime.h>

// CAGenerator: 64-step neural CA — ONE dispatch/step, H-half split.
// R19 (resubmit; previous run died to container-infra failure, not kernel):
//   R16 structure kept (256 blocks, 8 waves, 45-iter ring loop, same
//   barriers) but per-CU weight bytes halved. Block = (row-pair, half):
//   computes H channels [half*256, half*256+256) for rows y0,y0+1.
//   Wave w owns m-tile half*8+w: per ks ONE A-frag, two B-frags (row0/1),
//   two MFMAs. Phase 2: K=256 partial of W3*H; half0 writes
//   U = S + upd0 + b3, half1 writes Up = upd1. Consumers read U+Up.
//   No atomics, no extra dispatch. XCD = blk%8 -> each XCD sees one half's
//   weights (360 KB) only.
// kF: dout = (U63+Up63) ch0 * live63.
// Folded: Wc = W2@W1 (512x720), bc = W2@b1+b2. mask=uniform()<1.0 -> no RNG.

#define NPIX 8192
#define T_ALIVE 0.01f

typedef _Float16 f16;
typedef __attribute__((ext_vector_type(8)))  _Float16 h8_t;
typedef __attribute__((ext_vector_type(4)))  _Float16 h4_t;
typedef __attribute__((ext_vector_type(16))) float    fx16;

// ---------------------------------------------------------------------------
// Prep (R16/R17 versions)
// ---------------------------------------------------------------------------
__global__ __launch_bounds__(256) void tr512(
    const float* __restrict__ W2, float* __restrict__ W2T)
{
    __shared__ float t[32][33];
    const int bx = blockIdx.x & 15, by = blockIdx.x >> 4;
    const int x = threadIdx.x & 31, y8 = threadIdx.x >> 5;
#pragma unroll
    for (int r = 0; r < 32; r += 8)
        t[r + y8][x] = W2[(size_t)(by * 32 + r + y8) * 512 + bx * 32 + x];
    __syncthreads();
#pragma unroll
    for (int r = 0; r < 32; r += 8)
        W2T[(size_t)(bx * 32 + r + y8) * 512 + by * 32 + x] = t[x][r + y8];
}

__global__ __launch_bounds__(256) void wc32(
    const float* __restrict__ W2T, const float* __restrict__ W1,
    float* __restrict__ Wc)
{
    __shared__ float As[16][32];
    __shared__ float Bs[16][32];
    const int tid = threadIdx.x;
    const int ty = tid >> 3, tx = tid & 7;
    const int m0 = blockIdx.y * 32, n0 = blockIdx.x * 32;
    float acc[4] = {0.f, 0.f, 0.f, 0.f};

    for (int k0 = 0; k0 < 512; k0 += 16) {
#pragma unroll
        for (int t = 0; t < 2; ++t) {
            const int idx = tid + t * 256;
            const int r = idx >> 5, c = idx & 31;
            As[r][c] = W2T[(size_t)(k0 + r) * 512 + m0 + c];
            const int n = n0 + c;
            Bs[r][c] = (n < 720) ? W1[(size_t)(k0 + r) * 720 + n] : 0.f;
        }
        __syncthreads();
#pragma unroll
        for (int kk = 0; kk < 16; ++kk) {
            const float a = As[kk][ty];
#pragma unroll
            for (int j = 0; j < 4; ++j)
                acc[j] = fmaf(a, Bs[kk][tx * 4 + j], acc[j]);
        }
        __syncthreads();
    }
    const int m = m0 + ty;
#pragma unroll
    for (int j = 0; j < 4; ++j) {
        const int n = n0 + tx * 4 + j;
        if (n < 720) Wc[(size_t)m * 720 + n] = acc[j];
    }
}

__global__ __launch_bounds__(256) void bc_k(
    const float* __restrict__ W2, const float* __restrict__ b1,
    const float* __restrict__ b2, float* __restrict__ bc)
{
    const int m = blockIdx.x * 256 + threadIdx.x;
    if (m >= 512) return;
    float a = b2[m];
    for (int h = 0; h < 512; ++h) a += W2[m * 512 + h] * b1[h];
    bc[m] = a;
}

// 32x32x16 A-frags, K permuted (kp = tap*80+ci), 720 = 45*16 exactly.
__global__ __launch_bounds__(256) void swz_wc2(
    const float* __restrict__ Wc, f16* __restrict__ Wcsw2)
{
    const int idx = blockIdx.x * 256 + threadIdx.x;
    if (idx >= 45 * 16 * 64) return;
    const int lane = idx & 63;
    const int t = idx >> 6;
    const int mtg = t & 15, ks = t >> 4;
    const int m = mtg * 32 + (lane & 31);
    const int k0 = ks * 16 + (lane >> 5) * 8;
    h8_t v;
#pragma unroll
    for (int j = 0; j < 8; ++j) {
        const int kp = k0 + j;
        const int tap = kp / 80, ci = kp - tap * 80;
        v[j] = (f16)Wc[(size_t)m * 720 + ci * 9 + tap];
    }
    *(h8_t*)(Wcsw2 + (size_t)idx * 8) = v;
}

// 32x32x16 A-frags for W3 (80x512 padded to 96 rows).
__global__ __launch_bounds__(256) void swz_w32(
    const float* __restrict__ W3, f16* __restrict__ W3sw2)
{
    const int idx = blockIdx.x * 256 + threadIdx.x;
    if (idx >= 32 * 3 * 64) return;
    const int lane = idx & 63;
    const int t = idx >> 6;
    const int mt = t % 3, ks2 = t / 3;
    const int m = mt * 32 + (lane & 31);
    const int k0 = ks2 * 16 + (lane >> 5) * 8;
    h8_t v;
#pragma unroll
    for (int j = 0; j < 8; ++j)
        v[j] = (f16)((m < 80) ? W3[(size_t)m * 512 + k0 + j] : 0.f);
    *(h8_t*)(W3sw2 + (size_t)idx * 8) = v;
}

// Seed: U_{-1} := S_0 (fp32 ch-major), A_{-1} := S_0 ch0. Up_{-1} = 0 (memset).
__global__ __launch_bounds__(256) void seed2(
    const float* __restrict__ z, float* __restrict__ U0,
    float* __restrict__ A0)
{
    const int idx = blockIdx.x * 256 + threadIdx.x;
    if (idx >= 640) return;
    const int b = idx / 80, c = idx - b * 80;
    const int n = b * 1024 + 16 * 32 + 16;
    const float v = (c == 0) ? 1.f : z[b * 100 + (c - 1)];
    U0[(size_t)c * NPIX + n] = v;
    if (c == 0) A0[n] = 1.f;
}

// ---------------------------------------------------------------------------
// kS: one CA step, half the H channels, 2 rows. grid 256 x 512 thr.
//   blk: half = blk&1, g = blk>>1; b = g>>4, y0 = (g&15)*2.
// ---------------------------------------------------------------------------
__global__ __launch_bounds__(512) void kS(
    const f16* __restrict__ Wcsw2, const float* __restrict__ bc,
    const f16* __restrict__ W3sw2, const float* __restrict__ b3,
    const float* __restrict__ Uin, const float* __restrict__ Upin,
    const float* __restrict__ Ain,
    float* __restrict__ Uout, float* __restrict__ Upout,
    float* __restrict__ Aout)
{
    __shared__ f16   msT[10880];    // 10 cc x (4 rows x 34 px) x 8 halfs
    __shared__ f16   Hsw[16384];    // 32 octets x 64 px x 8 halfs = 32 KB
    __shared__ float bcL[256];
    __shared__ float b3L[80];
    __shared__ float SrowL[2][2560];// S_s own rows, fp32
    __shared__ float N6[192];       // (U+Up) ch0 rows y0-2..y0+3
    __shared__ float A6[192];       // alpha rows y0-2..y0+3
    __shared__ float live4[128];    // live rows y0-1..y0+2

    const int tid = threadIdx.x;
    const int lane = tid & 63, w = tid >> 6;     // w = 0..7
    const int li = lane & 31, q2 = lane >> 5;
    const int blk = blockIdx.x;
    const int half = blk & 1, g = blk >> 1;
    const int b = g >> 4, y0 = (g & 15) * 2;
    const int gb = b * 1024;
    const int mt = half * 8 + w;                 // this wave's m-tile (Wc)

    // early weight-ring prefetch (in flight during the build phase)
    h8_t aring[8];
#pragma unroll
    for (int pk = 0; pk < 8; ++pk)
        aring[pk] = *(const h8_t*)(Wcsw2 +
            (((size_t)pk * 16 + mt) * 64 + lane) * 8);

    if (tid < 256) bcL[tid] = bc[half * 256 + tid];
    if (tid < 80)  b3L[tid] = b3[tid];

    // ---------------- build phase ----------------------------------------
    if (tid < 192) {
        const int r = tid >> 5, x = tid & 31, yy = y0 - 2 + r;
        const bool ok = ((unsigned)yy < 32u);
        const int o = gb + yy * 32 + x;
        N6[tid] = ok ? (Uin[o] + Upin[o]) : -1e30f;
        A6[tid] = ok ? Ain[o] : -1e30f;
    }
    if (tid < 80) {  // zero halo columns xi = 0, 33 (all 4 msT rows)
        const int cc = tid >> 3, rem = tid & 7;
        const int r = rem >> 1, xi = (rem & 1) * 33;
        h8_t zz;
#pragma unroll
        for (int j = 0; j < 8; ++j) zz[j] = (f16)0.f;
        *(h8_t*)(msT + (size_t)(cc * 136 + r * 34 + xi) * 8) = zz;
    }
    __syncthreads();

    if (tid < 128) {  // live(r,x), rows y0-1..y0+2
        const int r = tid >> 5, x = tid & 31;
        float mN = -1e30f, mA = -1e30f;
#pragma unroll
        for (int rr = 0; rr < 3; ++rr)
#pragma unroll
            for (int dx = -1; dx <= 1; ++dx) {
                const int xx = x + dx;
                if ((unsigned)xx < 32u) {
                    mN = fmaxf(mN, N6[(r + rr) * 32 + xx]);
                    mA = fmaxf(mA, A6[(r + rr) * 32 + xx]);
                }
            }
        live4[tid] = (mN > T_ALIVE && mA > T_ALIVE) ? 1.f : 0.f;
    }
    __syncthreads();

    // S_s = (U+Up) * live: 4 rows x 80 ch x 32 px = 10240 elems
#pragma unroll
    for (int it = 0; it < 20; ++it) {
        const int e = tid + it * 512;
        const int x = e & 31;
        const int t2 = e >> 5;
        const int r = t2 / 80, ch = t2 - r * 80;
        const int yy = y0 - 1 + r;
        float v = 0.f;
        if ((unsigned)yy < 32u) {
            const size_t o = (size_t)ch * NPIX + gb + yy * 32 + x;
            v = (Uin[o] + Upin[o]) * live4[r * 32 + x];
        }
        msT[(size_t)((ch >> 3) * 136 + r * 34 + x + 1) * 8 + (ch & 7)] = (f16)v;
        if (r == 1 || r == 2) {
            SrowL[r - 1][ch * 32 + x] = v;
            if (ch == 0 && half == 0) Aout[gb + (y0 + r - 1) * 32 + x] = v;
        }
    }
    __syncthreads();

    // ---------------- phase 1: 32 H-ch x 64 px per wave -------------------
    int pxh[9];
#pragma unroll
    for (int t = 0; t < 9; ++t)
        pxh[t] = ((t / 3) * 34 + li + (t % 3)) * 8;

    fx16 acc0, acc1;
#pragma unroll
    for (int r = 0; r < 16; ++r) { acc0[r] = 0.f; acc1[r] = 0.f; }

#pragma unroll
    for (int ks = 0; ks < 45; ++ks) {
        const int o = 2 * ks + q2;
        const int ab = (o % 10) * 1088 + pxh[o / 10];
        const h8_t bf0 = *(const h8_t*)(msT + ab);        // row y0
        const h8_t bf1 = *(const h8_t*)(msT + ab + 272);  // row y0+1
        const h8_t av = aring[ks & 7];
        if (ks + 8 < 45)
            aring[ks & 7] = *(const h8_t*)(Wcsw2 +
                (((size_t)(ks + 8) * 16 + mt) * 64 + lane) * 8);
        acc0 = __builtin_amdgcn_mfma_f32_32x32x16_f16(av, bf0, acc0, 0, 0, 0);
        acc1 = __builtin_amdgcn_mfma_f32_32x32x16_f16(av, bf1, acc1, 0, 0, 0);
    }

    // relu(acc + bc) -> Hsw octets (co = local ch/8, px = r*32+li)
#pragma unroll
    for (int aa = 0; aa < 4; ++aa) {
        const int chl = 8 * aa + 4 * q2;
        const int co = w * 4 + aa;
        h4_t v0, v1;
#pragma unroll
        for (int rb = 0; rb < 4; ++rb) {
            const float bb = bcL[w * 32 + chl + rb];
            v0[rb] = (f16)fmaxf(acc0[aa * 4 + rb] + bb, 0.f);
            v1[rb] = (f16)fmaxf(acc1[aa * 4 + rb] + bb, 0.f);
        }
        *(h4_t*)(Hsw + ((size_t)co * 64 +      li) * 8 + 4 * q2) = v0;
        *(h4_t*)(Hsw + ((size_t)co * 64 + 32 + li) * 8 + 4 * q2) = v1;
    }
    __syncthreads();

    // ---------------- phase 2: upd_half = W3[:,halfK] * H (waves 0..5) ----
    if (w < 6) {
        const int m3 = w >> 1, r = w & 1;
        h8_t ar[8];
#pragma unroll
        for (int pk = 0; pk < 8; ++pk)
            ar[pk] = *(const h8_t*)(W3sw2 +
                (((size_t)(half * 16 + pk) * 3 + m3) * 64 + lane) * 8);

        fx16 acc3;
#pragma unroll
        for (int rr = 0; rr < 16; ++rr) acc3[rr] = 0.f;
#pragma unroll
        for (int i = 0; i < 16; ++i) {
            const h8_t bf = *(const h8_t*)(Hsw +
                ((size_t)(i * 2 + q2) * 64 + r * 32 + li) * 8);
            const h8_t a = ar[i & 7];
            if (i + 8 < 16)
                ar[i & 7] = *(const h8_t*)(W3sw2 +
                    (((size_t)(half * 16 + i + 8) * 3 + m3) * 64 + lane) * 8);
            acc3 = __builtin_amdgcn_mfma_f32_32x32x16_f16(a, bf, acc3, 0, 0, 0);
        }

        // half0: U = S + upd0 + b3 ; half1: Up = upd1
        const size_t px = (size_t)(gb + (y0 + r) * 32 + li);
#pragma unroll
        for (int aa = 0; aa < 4; ++aa)
#pragma unroll
            for (int rb = 0; rb < 4; ++rb) {
                const int ch = m3 * 32 + rb + 8 * aa + 4 * q2;
                if (ch < 80) {
                    const size_t idx = (size_t)ch * NPIX + px;
                    if (half == 0)
                        Uout[idx] = SrowL[r][ch * 32 + li]
                                  + acc3[aa * 4 + rb] + b3L[ch];
                    else
                        Upout[idx] = acc3[aa * 4 + rb];
                }
            }
    }
}

// ---------------------------------------------------------------------------
// kF: dout = (U63+Up63) ch0 * live63. grid 256 x 128 thr.
// ---------------------------------------------------------------------------
__global__ __launch_bounds__(128) void kF(
    const float* __restrict__ Uf, const float* __restrict__ Upf,
    const float* __restrict__ Af, float* __restrict__ dout)
{
    __shared__ float N3[96];
    __shared__ float A3[96];
    const int tid = threadIdx.x;
    const int blk = blockIdx.x;
    const int b = blk >> 5, y = blk & 31;
    const int gb = b * 1024;

    if (tid < 96) {
        const int r = tid >> 5, x = tid & 31, yy = y - 1 + r;
        const bool ok = ((unsigned)yy < 32u);
        const int o = gb + yy * 32 + x;
        N3[tid] = ok ? (Uf[o] + Upf[o]) : -1e30f;
        A3[tid] = ok ? Af[o] : -1e30f;
    }
    __syncthreads();

    if (tid < 32) {
        float mN = -1e30f, mA = -1e30f;
#pragma unroll
        for (int rr = 0; rr < 3; ++rr)
#pragma unroll
            for (int dx = -1; dx <= 1; ++dx) {
                const int xx = tid + dx;
                if ((unsigned)xx < 32u) {
                    mN = fmaxf(mN, N3[rr * 32 + xx]);
                    mA = fmaxf(mA, A3[rr * 32 + xx]);
                }
            }
        const float lv = (mN > T_ALIVE && mA > T_ALIVE) ? 1.f : 0.f;
        const int o = gb + y * 32 + tid;
        dout[o] = (Uf[o] + Upf[o]) * lv;
    }
}

// ---------------------------------------------------------------------------
extern "C" void kernel_launch(void* const* d_in, const int* in_sizes, int n_in,
                              void* d_out, int out_size, void* d_ws, size_t ws_size,
                              hipStream_t stream)
{
    const float* z  = (const float*)d_in[0];
    const float* W1 = (const float*)d_in[1];   // 512 x 720
    const float* b1 = (const float*)d_in[2];
    const float* W2 = (const float*)d_in[3];   // 512 x 512
    const float* b2 = (const float*)d_in[4];
    const float* W3 = (const float*)d_in[5];   // 80 x 512
    const float* b3 = (const float*)d_in[6];

    char* ws = (char*)d_ws;
    float* U0    = (float*)ws;  ws += (size_t)80 * NPIX * 4;
    float* U1    = (float*)ws;  ws += (size_t)80 * NPIX * 4;
    float* Up0   = (float*)ws;  ws += (size_t)80 * NPIX * 4;
    float* Up1   = (float*)ws;  ws += (size_t)80 * NPIX * 4;
    float* A0    = (float*)ws;  ws += (size_t)NPIX * 4;
    float* A1    = (float*)ws;  ws += (size_t)NPIX * 4;
    float* bc    = (float*)ws;  ws += 512 * 4;
    float* Wc    = (float*)ws;  ws += (size_t)512 * 720 * 4;
    float* W2T   = (float*)ws;  ws += (size_t)512 * 512 * 4;
    f16*   Wcsw2 = (f16*)ws;   ws += (size_t)45 * 16 * 64 * 8 * 2;
    f16*   W3sw2 = (f16*)ws;   ws += (size_t)32 * 3 * 64 * 8 * 2;

    hipMemsetAsync(U0, 0, (size_t)80 * NPIX * 4, stream);
    hipMemsetAsync(Up0, 0, (size_t)80 * NPIX * 4, stream);
    hipMemsetAsync(A0, 0, (size_t)NPIX * 4, stream);
    seed2<<<3, 256, 0, stream>>>(z, U0, A0);
    tr512<<<256, 256, 0, stream>>>(W2, W2T);
    wc32<<<dim3(23, 16), 256, 0, stream>>>(W2T, W1, Wc);
    bc_k<<<2, 256, 0, stream>>>(W2, b1, b2, bc);
    swz_wc2<<<180, 256, 0, stream>>>(Wc, Wcsw2);
    swz_w32<<<24, 256, 0, stream>>>(W3, W3sw2);

    float* Uc = U0;   float* Un = U1;
    float* Upc = Up0; float* Upn = Up1;
    float* Ac = A0;   float* An = A1;
    for (int s = 0; s < 64; ++s) {
        kS<<<256, 512, 0, stream>>>(Wcsw2, bc, W3sw2, b3,
                                    Uc, Upc, Ac, Un, Upn, An);
        float* t;
        t = Uc;  Uc = Un;   Un = t;
        t = Upc; Upc = Upn; Upn = t;
        t = Ac;  Ac = An;   An = t;
    }
    kF<<<256, 128, 0, stream>>>(Uc, Upc, Ac, (float*)d_out);
}